// Round 1
// 264.943 us; speedup vs baseline: 1.0328x; 1.0328x over previous
//
#include <hip/hip_runtime.h>
#include <hip/hip_bf16.h>
#include <math.h>

#define NT 2048
#define EMBD 512
#define NH 8
#define QKV_LD 1536
#define KSPLIT 4

typedef unsigned short u16;
typedef __attribute__((ext_vector_type(8))) short short8;
typedef __attribute__((ext_vector_type(4))) float v4f;

static __device__ __forceinline__ float bf2f(unsigned int u) {
    union { unsigned int i; float f; } c; c.i = u << 16; return c.f;
}
static __device__ __forceinline__ unsigned int f2bf(float x) {   // RNE
    union { float f; unsigned int u; } c; c.f = x;
    return (c.u + 0x7fffu + ((c.u >> 16) & 1u)) >> 16;
}

// ------- split x into bf16 hi/lo --------------------------------------------
__global__ __launch_bounds__(256) void split_x(const float* __restrict__ x,
    u16* __restrict__ xh, u16* __restrict__ xl)
{
    int i = (blockIdx.x * 256 + threadIdx.x) << 2;
    float4 v = *(const float4*)(x + i);
    float f[4] = {v.x, v.y, v.z, v.w};
    unsigned int hi[4], lo[4];
#pragma unroll
    for (int j = 0; j < 4; ++j) {
        hi[j] = f2bf(f[j]);
        lo[j] = f2bf(f[j] - bf2f(hi[j]));
    }
    uint2 wh; wh.x = hi[0] | (hi[1] << 16); wh.y = hi[2] | (hi[3] << 16);
    uint2 wl; wl.x = lo[0] | (lo[1] << 16); wl.y = lo[2] | (lo[3] << 16);
    *(uint2*)(xh + i) = wh;
    *(uint2*)(xl + i) = wl;
}

// ------- split+transpose W[K][N] -> Wt[n][k] bf16 hi/lo (row stride ld) -----
__global__ __launch_bounds__(256) void split_wt(const float* __restrict__ W,
    u16* __restrict__ wth, u16* __restrict__ wtl, int ld)
{
    __shared__ float tile[64][65];
    const int n0 = blockIdx.x << 6, k0 = blockIdx.y << 6;
    const int t = threadIdx.x;
    const int r = t >> 2, c4 = (t & 3) << 4;
#pragma unroll
    for (int j = 0; j < 4; ++j)
        *(float4*)&tile[r][c4 + (j << 2)] =
            *(const float4*)(W + (size_t)(k0 + r) * ld + n0 + c4 + (j << 2));
    __syncthreads();
    const int n_l = t >> 2;
    u16 th[16], tl[16];
#pragma unroll
    for (int j = 0; j < 16; ++j) {
        float f = tile[c4 + j][n_l];
        unsigned int h = f2bf(f);
        th[j] = (u16)h;
        tl[j] = (u16)f2bf(f - bf2f(h));
    }
    u16* dh = wth + (size_t)(n0 + n_l) * EMBD + k0 + c4;
    u16* dl = wtl + (size_t)(n0 + n_l) * EMBD + k0 + c4;
    *(uint4*)dh       = *(uint4*)&th[0];
    *(uint4*)(dh + 8) = *(uint4*)&th[8];
    *(uint4*)dl       = *(uint4*)&tl[0];
    *(uint4*)(dl + 8) = *(uint4*)&tl[8];
}

// ------- qkv = x @ Wqkv + b via split-precision bf16 MFMA -------------------
__global__ __launch_bounds__(256) void gemm_qkv_mfma(const u16* __restrict__ xh,
    const u16* __restrict__ xl, const u16* __restrict__ wth,
    const u16* __restrict__ wtl, const float* __restrict__ bias,
    u16* __restrict__ qkvb)
{
    const int n0 = blockIdx.x << 6, m0 = blockIdx.y << 6;
    const int w = threadIdx.x >> 6, lane = threadIdx.x & 63;
    const int wm = w >> 1, wn = w & 1;
    const int fr = lane & 15, kd = (lane >> 4) << 3;

    const u16* ah0 = xh + (size_t)(m0 + wm * 32 + fr) * EMBD + kd;
    const u16* al0 = xl + (size_t)(m0 + wm * 32 + fr) * EMBD + kd;
    const u16* bh0 = wth + (size_t)(n0 + wn * 32 + fr) * EMBD + kd;
    const u16* bl0 = wtl + (size_t)(n0 + wn * 32 + fr) * EMBD + kd;

    v4f acc[2][2] = {};
    for (int kc = 0; kc < EMBD; kc += 32) {
        short8 a_h[2], a_l[2], b_h[2], b_l[2];
#pragma unroll
        for (int im = 0; im < 2; ++im) {
            a_h[im] = *(const short8*)(ah0 + (size_t)im * 16 * EMBD + kc);
            a_l[im] = *(const short8*)(al0 + (size_t)im * 16 * EMBD + kc);
        }
#pragma unroll
        for (int in = 0; in < 2; ++in) {
            b_h[in] = *(const short8*)(bh0 + (size_t)in * 16 * EMBD + kc);
            b_l[in] = *(const short8*)(bl0 + (size_t)in * 16 * EMBD + kc);
        }
#pragma unroll
        for (int im = 0; im < 2; ++im)
#pragma unroll
            for (int in = 0; in < 2; ++in) {
                acc[im][in] = __builtin_amdgcn_mfma_f32_16x16x32_bf16(a_h[im], b_h[in], acc[im][in], 0, 0, 0);
                acc[im][in] = __builtin_amdgcn_mfma_f32_16x16x32_bf16(a_h[im], b_l[in], acc[im][in], 0, 0, 0);
                acc[im][in] = __builtin_amdgcn_mfma_f32_16x16x32_bf16(a_l[im], b_h[in], acc[im][in], 0, 0, 0);
            }
    }
    const int qr = (lane >> 4) << 2;
#pragma unroll
    for (int im = 0; im < 2; ++im)
#pragma unroll
        for (int in = 0; in < 2; ++in) {
            int n = n0 + wn * 32 + in * 16 + fr;
            float bv = bias[n];
#pragma unroll
            for (int r = 0; r < 4; ++r) {
                int m = m0 + wm * 32 + im * 16 + qr + r;
                qkvb[(size_t)m * QKV_LD + n] = (u16)f2bf(acc[im][in][r] + bv);
            }
        }
}

// ------- V transpose: Vt[h][t][k] <- qkv[k][h*192+128+t] ------------------
__global__ __launch_bounds__(256) void transpose_v(const u16* __restrict__ qkvb,
                                                   u16* __restrict__ Vt)
{
    __shared__ u16 tile[64][72];
    const int h = blockIdx.y, k0 = blockIdx.x << 6;
    const int t = threadIdx.x;
    {
        int r = t >> 2, cg = (t & 3) << 4;
        const u16* src = qkvb + (size_t)(k0 + r) * QKV_LD + h * 192 + 128 + cg;
        *(uint4*)&tile[r][cg]     = *(const uint4*)src;
        *(uint4*)&tile[r][cg + 8] = *(const uint4*)(src + 8);
    }
    __syncthreads();
    {
        int c = t >> 2, kg = (t & 3) << 4;
        u16 tmp[16];
#pragma unroll
        for (int j = 0; j < 16; ++j) tmp[j] = tile[kg + j][c];
        u16* dst = Vt + ((size_t)h * 64 + c) * NT + k0 + kg;
        *(uint4*)dst       = *(uint4*)&tmp[0];
        *(uint4*)(dst + 8) = *(uint4*)&tmp[8];
    }
}

// ==== fused attention: QK^T -> exp/z -> (+bias via MFMA projection) -> PV ===
// y_partial = exp(s)@V  (accP, needs /z later)  and  bias@V (accB), split-K=4.
// Per block: 32 q-rows x all 8 heads (wave = head), k-chunks of 64.
// bias tile & P tile share one LDS buffer [8 heads][32 q][64 k] bf16 with
// XOR-granule swizzle (granule = 8 u16 = 16B): kg' = kg ^ (q&7) -> conflict-
// free ds_read_b128 A-fragments (row stride 128B otherwise = 32-way, G4).
// Angle/phase/sincos numerics FROZEN (transplanted verbatim from R3 path).
__global__ __launch_bounds__(512, 2) void fused_attn(
    const u16* __restrict__ qkvb, const u16* __restrict__ Vt,
    const float* __restrict__ vec, const float* __restrict__ Wb,
    const float* __restrict__ bb, float* __restrict__ zpart,
    float* __restrict__ partsP, float* __restrict__ partsB)
{
    __shared__ float flds[32];
    __shared__ float vql[96];
    __shared__ float ang[32 * 65];
    __shared__ u16 tile[8 * 2056];     // head stride 2056 u16 (+8 pad: bank skew)

    // XCD-aware decode: blocks on one XCD share a k-split -> K/V slice L2-fits
    const int bid = blockIdx.x;
    const int xcd = bid & 7;
    const int zsp = xcd >> 1;                       // 0..3 k-split
    const int qt  = ((bid >> 3) << 1) | (xcd & 1);  // 0..63 q-tile
    const int q0 = qt << 5;
    const int kbase = zsp << 9;

    const int t = threadIdx.x;
    const int w = t >> 6;              // wave = head
    const int lane = t & 63;
    const int fr = lane & 15;
    const int hi4 = lane >> 4;
    const int kd = hi4 << 3;
    const int qr = hi4 << 2;

    if (t < 32) flds[t] = __fdiv_rn(__fdiv_rn((float)t, 31.0f), 0.1f);
    else if (t < 128) vql[t - 32] = vec[q0 * 3 + (t - 32)];

    // projection B-frags (rows 0..31 sin, 32..63 cos of Wb[64][8])
    short8 BS, BC;
#pragma unroll
    for (int j = 0; j < 8; ++j) {
        float ws = (fr < 8) ? Wb[(kd + j) * 8 + fr] : 0.0f;
        float wc = (fr < 8) ? Wb[(32 + kd + j) * 8 + fr] : 0.0f;
        BS[j] = (short)f2bf(ws);
        BC[j] = (short)f2bf(wc);
    }
    const float bbv = (fr < 8) ? bb[fr] : 0.0f;

    // Q fragments for head w (k-invariant)
    short8 aq[2][2];
#pragma unroll
    for (int mb = 0; mb < 2; ++mb)
#pragma unroll
        for (int kk = 0; kk < 2; ++kk)
            aq[mb][kk] = *(const short8*)(qkvb +
                (size_t)(q0 + mb * 16 + fr) * QKV_LD + w * 192 + kk * 32 + kd);

    v4f accP[2][4] = {};
    v4f accB[2][4] = {};
    float zacc[2][4] = {};

    __syncthreads();

    for (int c = 0; c < 8; ++c) {
        const int kc = kbase + (c << 6);
        // ---- phase A: angles, 4 pairs/thread (vec_k straight from L2)
        {
            const int p0 = t << 2;
            const int q = p0 >> 6;
            const int kl = p0 & 63;
            const float a0 = vql[q * 3], a1 = vql[q * 3 + 1], a2 = vql[q * 3 + 2];
            const float* vk = vec + (size_t)(kc + kl) * 3;
#pragma unroll
            for (int j = 0; j < 4; ++j) {
                float c0 = vk[j * 3], c1 = vk[j * 3 + 1], c2 = vk[j * 3 + 2];
                float dot = __fadd_rn(__fadd_rn(__fmul_rn(a0, c0), __fmul_rn(a1, c1)),
                                      __fmul_rn(a2, c2));
                float dotc = fminf(fmaxf(dot, 0.0f), 1.0f);
                ang[q * 65 + kl + j] = __fdiv_rn(acosf(dotc), 0.001f);
            }
        }
        __syncthreads();
        // ---- phase B: sincos features -> MFMA projection -> bias tile (bf16)
#pragma unroll
        for (int gi = 0; gi < 16; ++gi) {
            const int g = w + (gi << 3);
            const int q = g >> 2;
            const int ksub = (g & 3) << 4;
            const float av = ang[q * 65 + ksub + fr];
            short8 AS, AC;
#pragma unroll
            for (int j = 0; j < 8; ++j) {
                float ph = __fmul_rn(flds[kd + j], av);
                float rv = ph * 0.15915494309189535f;
                float rf = rv - floorf(rv);
                AS[j] = (short)f2bf(__builtin_amdgcn_sinf(rf));
                AC[j] = (short)f2bf(__builtin_amdgcn_cosf(rf));
            }
            v4f cb = {};
            cb = __builtin_amdgcn_mfma_f32_16x16x32_bf16(AS, BS, cb, 0, 0, 0);
            cb = __builtin_amdgcn_mfma_f32_16x16x32_bf16(AC, BC, cb, 0, 0, 0);
            if (fr < 8) {   // lane fr = head, rows qr..qr+3 = pair-in-group
                const int kg = (ksub + qr) >> 3;
                unsigned int pk0 = f2bf(cb[0] + bbv) | (f2bf(cb[1] + bbv) << 16);
                unsigned int pk1 = f2bf(cb[2] + bbv) | (f2bf(cb[3] + bbv) << 16);
                uint2 wv; wv.x = pk0; wv.y = pk1;
                *(uint2*)&tile[fr * 2056 + q * 64 + ((kg ^ (q & 7)) << 3) + (qr & 7)] = wv;
            }
        }
        __syncthreads();
        // ---- phase C: V/K frags; accB += bias@V; QK^T; exp + z
        short8 vb[4][2], bk[4][2];
#pragma unroll
        for (int nt = 0; nt < 4; ++nt)
#pragma unroll
            for (int kk = 0; kk < 2; ++kk) {
                vb[nt][kk] = *(const short8*)(Vt +
                    (size_t)(w * 64 + nt * 16 + fr) * NT + kc + kk * 32 + kd);
                bk[nt][kk] = *(const short8*)(qkvb +
                    (size_t)(kc + nt * 16 + fr) * QKV_LD + w * 192 + 64 + kk * 32 + kd);
            }
#pragma unroll
        for (int mb = 0; mb < 2; ++mb) {
            const int q = mb * 16 + fr;
#pragma unroll
            for (int kk = 0; kk < 2; ++kk) {
                short8 ab = *(const short8*)&tile[w * 2056 + q * 64 +
                    (((kk * 4 + hi4) ^ (q & 7)) << 3)];
#pragma unroll
                for (int nt = 0; nt < 4; ++nt)
                    accB[mb][nt] = __builtin_amdgcn_mfma_f32_16x16x32_bf16(ab, vb[nt][kk], accB[mb][nt], 0, 0, 0);
            }
        }
        v4f sacc[2][4] = {};
#pragma unroll
        for (int mb = 0; mb < 2; ++mb)
#pragma unroll
            for (int nt = 0; nt < 4; ++nt) {
                sacc[mb][nt] = __builtin_amdgcn_mfma_f32_16x16x32_bf16(aq[mb][0], bk[nt][0], sacc[mb][nt], 0, 0, 0);
                sacc[mb][nt] = __builtin_amdgcn_mfma_f32_16x16x32_bf16(aq[mb][1], bk[nt][1], sacc[mb][nt], 0, 0, 0);
            }
        unsigned int pk[2][4][2];
#pragma unroll
        for (int mb = 0; mb < 2; ++mb)
#pragma unroll
            for (int nt = 0; nt < 4; ++nt)
#pragma unroll
                for (int r2 = 0; r2 < 2; ++r2) {
                    float e0 = __expf(sacc[mb][nt][2 * r2] * 0.125f);
                    float e1 = __expf(sacc[mb][nt][2 * r2 + 1] * 0.125f);
                    zacc[mb][2 * r2] += e0;
                    zacc[mb][2 * r2 + 1] += e1;
                    pk[mb][nt][r2] = f2bf(e0) | (f2bf(e1) << 16);
                }
        __syncthreads();
        // ---- phase D: P -> tile (bf16, swizzled)
#pragma unroll
        for (int mb = 0; mb < 2; ++mb)
#pragma unroll
            for (int nt = 0; nt < 4; ++nt) {
                const int kg = (nt << 1) + (fr >> 3);
#pragma unroll
                for (int r = 0; r < 4; ++r) {
                    const int q = mb * 16 + qr + r;
                    tile[w * 2056 + q * 64 + ((kg ^ (q & 7)) << 3) + (fr & 7)] =
                        (u16)(pk[mb][nt][r >> 1] >> ((r & 1) << 4));
                }
            }
        __syncthreads();
        // ---- phase E: accP += P@V (reuse vb regs)
#pragma unroll
        for (int mb = 0; mb < 2; ++mb) {
            const int q = mb * 16 + fr;
#pragma unroll
            for (int kk = 0; kk < 2; ++kk) {
                short8 ap = *(const short8*)&tile[w * 2056 + q * 64 +
                    (((kk * 4 + hi4) ^ (q & 7)) << 3)];
#pragma unroll
                for (int nt = 0; nt < 4; ++nt)
                    accP[mb][nt] = __builtin_amdgcn_mfma_f32_16x16x32_bf16(ap, vb[nt][kk], accP[mb][nt], 0, 0, 0);
            }
        }
    }
    // ---- epilogue: z reduce (over 16 fr lanes) + partial writes
#pragma unroll
    for (int off = 1; off < 16; off <<= 1)
#pragma unroll
        for (int mb = 0; mb < 2; ++mb)
#pragma unroll
            for (int r = 0; r < 4; ++r)
                zacc[mb][r] += __shfl_xor(zacc[mb][r], off);
    if (fr == 0) {
#pragma unroll
        for (int mb = 0; mb < 2; ++mb)
#pragma unroll
            for (int r = 0; r < 4; ++r)
                zpart[((size_t)zsp * 8 + w) * NT + q0 + mb * 16 + qr + r] = zacc[mb][r];
    }
    float* pP = partsP + (size_t)zsp * NT * EMBD;
    float* pB = partsB + (size_t)zsp * NT * EMBD;
#pragma unroll
    for (int mb = 0; mb < 2; ++mb)
#pragma unroll
        for (int nt = 0; nt < 4; ++nt)
#pragma unroll
            for (int r = 0; r < 4; ++r) {
                const size_t idx = (size_t)(q0 + mb * 16 + qr + r) * EMBD +
                                   (w << 6) + (nt << 4) + fr;
                pP[idx] = accP[mb][nt][r];
                pB[idx] = accB[mb][nt][r];
            }
}

// ------- reduce 4 partials: y = sumP/sumZ + sumB -> bf16 hi/lo --------------
__global__ __launch_bounds__(256) void reduce_y2(const float* __restrict__ partsP,
    const float* __restrict__ partsB, const float* __restrict__ zpart,
    u16* __restrict__ yh, u16* __restrict__ yl)
{
    const int MN = NT * EMBD;
    int i = (blockIdx.x * 256 + threadIdx.x) << 2;
    const int q = i >> 9;
    const int h = (i & 511) >> 6;
    float zs = 0.0f;
#pragma unroll
    for (int z = 0; z < KSPLIT; ++z) zs += zpart[((size_t)z * 8 + h) * NT + q];
    float4 aP = *(const float4*)(partsP + i);
    float4 aB = *(const float4*)(partsB + i);
#pragma unroll
    for (int z = 1; z < KSPLIT; ++z) {
        float4 p = *(const float4*)(partsP + (size_t)z * MN + i);
        float4 b = *(const float4*)(partsB + (size_t)z * MN + i);
        aP.x += p.x; aP.y += p.y; aP.z += p.z; aP.w += p.w;
        aB.x += b.x; aB.y += b.y; aB.z += b.z; aB.w += b.w;
    }
    const float iz = 1.0f / zs;
    float f[4] = {aP.x * iz + aB.x, aP.y * iz + aB.y,
                  aP.z * iz + aB.z, aP.w * iz + aB.w};
    unsigned int hi[4], lo[4];
#pragma unroll
    for (int j = 0; j < 4; ++j) {
        hi[j] = f2bf(f[j]);
        lo[j] = f2bf(f[j] - bf2f(hi[j]));
    }
    uint2 wh; wh.x = hi[0] | (hi[1] << 16); wh.y = hi[2] | (hi[3] << 16);
    uint2 wl; wl.x = lo[0] | (lo[1] << 16); wl.y = lo[2] | (lo[3] << 16);
    *(uint2*)(yh + i) = wh;
    *(uint2*)(yl + i) = wl;
}

// ------- out = y @ Wout + bout via split-precision bf16 MFMA ----------------
__global__ __launch_bounds__(256) void gemm_out_mfma(const u16* __restrict__ yh,
    const u16* __restrict__ yl, const u16* __restrict__ wh,
    const u16* __restrict__ wl, const float* __restrict__ bias,
    float* __restrict__ out)
{
    const int n0 = blockIdx.x << 6, m0 = blockIdx.y << 6;
    const int w = threadIdx.x >> 6, lane = threadIdx.x & 63;
    const int wm = w >> 1, wn = w & 1;
    const int fr = lane & 15, kd = (lane >> 4) << 3;

    const u16* ah0 = yh + (size_t)(m0 + wm * 32 + fr) * EMBD + kd;
    const u16* al0 = yl + (size_t)(m0 + wm * 32 + fr) * EMBD + kd;
    const u16* bh0 = wh + (size_t)(n0 + wn * 32 + fr) * EMBD + kd;
    const u16* bl0 = wl + (size_t)(n0 + wn * 32 + fr) * EMBD + kd;

    v4f acc[2][2] = {};
    for (int kc = 0; kc < EMBD; kc += 32) {
        short8 a_h[2], a_l[2], b_h[2], b_l[2];
#pragma unroll
        for (int im = 0; im < 2; ++im) {
            a_h[im] = *(const short8*)(ah0 + (size_t)im * 16 * EMBD + kc);
            a_l[im] = *(const short8*)(al0 + (size_t)im * 16 * EMBD + kc);
        }
#pragma unroll
        for (int in = 0; in < 2; ++in) {
            b_h[in] = *(const short8*)(bh0 + (size_t)in * 16 * EMBD + kc);
            b_l[in] = *(const short8*)(bl0 + (size_t)in * 16 * EMBD + kc);
        }
#pragma unroll
        for (int im = 0; im < 2; ++im)
#pragma unroll
            for (int in = 0; in < 2; ++in) {
                acc[im][in] = __builtin_amdgcn_mfma_f32_16x16x32_bf16(a_h[im], b_h[in], acc[im][in], 0, 0, 0);
                acc[im][in] = __builtin_amdgcn_mfma_f32_16x16x32_bf16(a_h[im], b_l[in], acc[im][in], 0, 0, 0);
                acc[im][in] = __builtin_amdgcn_mfma_f32_16x16x32_bf16(a_l[im], b_h[in], acc[im][in], 0, 0, 0);
            }
    }
    const int qr = (lane >> 4) << 2;
#pragma unroll
    for (int im = 0; im < 2; ++im)
#pragma unroll
        for (int in = 0; in < 2; ++in) {
            int n = n0 + wn * 32 + in * 16 + fr;
            float bv = bias[n];
#pragma unroll
            for (int r = 0; r < 4; ++r) {
                int m = m0 + wm * 32 + im * 16 + qr + r;
                out[(size_t)m * EMBD + n] = acc[im][in][r] + bv;
            }
        }
}

extern "C" void kernel_launch(void* const* d_in, const int* in_sizes, int n_in,
                              void* d_out, int out_size, void* d_ws, size_t ws_size,
                              hipStream_t stream)
{
    const float* x    = (const float*)d_in[0];
    const float* vec  = (const float*)d_in[1];
    const float* Wqkv = (const float*)d_in[2];
    const float* bqkv = (const float*)d_in[3];
    const float* Wb   = (const float*)d_in[4];
    const float* bb   = (const float*)d_in[5];
    const float* Wout = (const float*)d_in[6];
    const float* bout = (const float*)d_in[7];
    float* out = (float*)d_out;

    char* ws = (char*)d_ws;
    u16*   qkvb   = (u16*)(ws);                     //  6,291,456
    u16*   Vt     = (u16*)(ws + 6291456);           //  2,097,152
    float* zpart  = (float*)(ws + 8388608);         //    262,144 (4*8*2048*4)
    float* partsP = (float*)(ws + 8650752);         // 16,777,216
    float* partsB = (float*)(ws + 25427968);        // 16,777,216
    u16*   yh     = (u16*)(ws + 42205184);          //  2,097,152
    u16*   yl     = (u16*)(ws + 44302336);          //  2,097,152
    // transients (consumed before region reuse):
    u16*   xh     = (u16*)(ws + 46399488);          //  2,097,152
    u16*   xl     = (u16*)(ws + 48496640);          //  2,097,152
    u16*   wth    = (u16*)(ws + 50593792);          //  1,572,864
    u16*   wtl    = (u16*)(ws + 52166656);          //  1,572,864
    u16*   woth   = (u16*)(ws + 46399488);          // alias xh (after fused)
    u16*   wotl   = (u16*)(ws + 46923776);          // total: 53,739,520 B

    split_x<<<1024, 256, 0, stream>>>(x, xh, xl);
    split_wt<<<dim3(24, 8), 256, 0, stream>>>(Wqkv, wth, wtl, QKV_LD);
    gemm_qkv_mfma<<<dim3(24, 32), 256, 0, stream>>>(xh, xl, wth, wtl, bqkv, qkvb);
    transpose_v<<<dim3(32, 8), 256, 0, stream>>>(qkvb, Vt);
    fused_attn<<<64 * KSPLIT, 512, 0, stream>>>(qkvb, Vt, vec, Wb, bb,
                                                zpart, partsP, partsB);
    reduce_y2<<<1024, 256, 0, stream>>>(partsP, partsB, zpart, yh, yl);
    split_wt<<<dim3(8, 8), 256, 0, stream>>>(Wout, woth, wotl, EMBD);
    gemm_out_mfma<<<dim3(8, 32), 256, 0, stream>>>(yh, yl, woth, wotl, bout, out);
}